// Round 3
// baseline (182.380 us; speedup 1.0000x reference)
//
#include <hip/hip_runtime.h>
#include <hip/hip_bf16.h>
#include <stdint.h>

typedef __attribute__((ext_vector_type(8))) short short8;
typedef __attribute__((ext_vector_type(4))) float f32x4;
typedef __attribute__((ext_vector_type(4))) int i32x4;

#define HWORDS 25600  // u32 words per private histogram (covers N <= 102400 as u8)

static __device__ __forceinline__ short to_bf16s(float f) {
  __hip_bfloat16 h = __float2bfloat16(f);
  return __builtin_bit_cast(short, h);
}

// ---------------------------------------------------------------------------
// Histogram of src = edge_index[0] (dst is algebraically unused: the final
// mean over all nodes collapses segment_sum to sum_e h[src[e]]).
// Per-block FULL-RANGE u8 histogram in LDS (100KB) -> zero global atomics on
// the per-edge path. Each block stores its private histogram; k_mid merges.
__global__ __launch_bounds__(1024) void k_h1(const int* __restrict__ e,
                                             unsigned* __restrict__ priv,
                                             unsigned* __restrict__ spill,
                                             int E) {
  __shared__ unsigned cnt[HWORDS];
  __shared__ int is64s;
  int tid = threadIdx.x;
  if (tid < 64) {  // layout detect: int64 -> high dwords all zero (LE)
    unsigned long long b = __ballot(e[2 * tid + 1] == 0);
    if (tid == 0) is64s = (__popcll(b) > 32) ? 1 : 0;
  }
  for (int j = tid; j < HWORDS; j += 1024) cnt[j] = 0u;
  __syncthreads();
  int is64 = is64s;

  int nq = E >> 2;
  int stride = gridDim.x * 1024;
  for (int q = blockIdx.x * 1024 + tid; q < nq; q += stride) {
    i32x4 v;
    if (is64) {
      i32x4 a = *reinterpret_cast<const i32x4*>(e + 8 * (size_t)q);
      i32x4 b = *reinterpret_cast<const i32x4*>(e + 8 * (size_t)q + 4);
      v = i32x4{a[0], a[2], b[0], b[2]};
    } else {
      v = *reinterpret_cast<const i32x4*>(e + 4 * (size_t)q);
    }
#pragma unroll
    for (int k = 0; k < 4; ++k) {
      unsigned n = (unsigned)v[k];
      unsigned sh = (n & 3u) * 8u;
      unsigned old = atomicAdd(&cnt[n >> 2], 1u << sh);
      if (((old >> sh) & 0xFFu) == 0xFFu) {  // rare u8 saturation: back out
        atomicSub(&cnt[n >> 2], 1u << sh);
        atomicAdd(&spill[n], 1u);
      }
    }
  }
  int tail = E & 3;
  if (blockIdx.x == 0 && tid < tail) {
    int idx = E - tail + tid;
    unsigned n = (unsigned)(is64 ? e[2 * idx] : e[idx]);
    unsigned sh = (n & 3u) * 8u;
    unsigned old = atomicAdd(&cnt[n >> 2], 1u << sh);
    if (((old >> sh) & 0xFFu) == 0xFFu) {
      atomicSub(&cnt[n >> 2], 1u << sh);
      atomicAdd(&spill[n], 1u);
    }
  }
  __syncthreads();
  unsigned* dst = priv + (size_t)blockIdx.x * HWORDS;
  for (int j = tid; j < HWORDS; j += 1024) dst[j] = cnt[j];
}

// Fallback when ws too small: old device-atomic histogram into spill.
__global__ __launch_bounds__(256) void k_hist_fb(const int* __restrict__ e,
                                                 unsigned* __restrict__ deg, int E) {
  __shared__ int is64s;
  int tid = threadIdx.x;
  if (tid < 64) {
    unsigned long long b = __ballot(e[2 * tid + 1] == 0);
    if (tid == 0) is64s = (__popcll(b) > 32) ? 1 : 0;
  }
  __syncthreads();
  int is64 = is64s;
  int stride = gridDim.x * blockDim.x;
  for (int i = blockIdx.x * blockDim.x + tid; i < E; i += stride)
    atomicAdd(&deg[is64 ? (unsigned)e[2 * i] : (unsigned)e[i]], 1u);
}

// ---------------------------------------------------------------------------
// Blocks [0,64): W1 (f32 [128][128], h=x@W1) -> bf16 B-fragments for
//   mfma_f32_16x16x32_bf16. slot=(ct*4+ks)*64+lane holds 8 bf16:
//   col = ct*16+(lane&15), k = ks*32+(lane>>4)*8+e.
// Blocks [64,..): merge B1 private u8 histograms -> wdeg = 1 + deg (+spill).
// Word-sum trick: per-byte totals = true degree < 256 -> no cross-byte carry.
__global__ __launch_bounds__(256) void k_mid(const float* __restrict__ W1,
                                             short* __restrict__ frag,
                                             const unsigned* __restrict__ priv,
                                             const unsigned* __restrict__ spill,
                                             float* __restrict__ wdeg,
                                             int N, int B1) {
  int b = blockIdx.x;
  if (b < 64) {
    int idx = b * 256 + threadIdx.x;  // k*128 + col
    int k = idx >> 7, col = idx & 127;
    int ct = col >> 4, ks = k >> 5, lh = (k >> 3) & 3, e = k & 7;
    int lane = lh * 16 + (col & 15);
    frag[((ct * 4 + ks) * 64 + lane) * 8 + e] = to_bf16s(W1[idx]);
  } else {
    int w = (b - 64) * 256 + threadIdx.x;  // word id = 4 nodes
    int nw = (N + 3) >> 2;
    if (w < nw) {
      unsigned s = 0;
      for (int c = 0; c < B1; ++c) s += priv[(size_t)c * HWORDS + w];
      int n0 = w << 2;
      f32x4 o;
      o[0] = 1.0f + (float)(s & 0xFFu) + (float)spill[n0 + 0];
      o[1] = 1.0f + (float)((s >> 8) & 0xFFu) + (float)spill[n0 + 1];
      o[2] = 1.0f + (float)((s >> 16) & 0xFFu) + (float)spill[n0 + 2];
      o[3] = 1.0f + (float)(s >> 24) + (float)spill[n0 + 3];
      *reinterpret_cast<f32x4*>(wdeg + n0) = o;
    }
  }
}

// ---------------------------------------------------------------------------
// Main: s[j] = sum_n wdeg[n] * relu( (X@W1)[n][j] + b1[j] ),  j = 0..127.
// Per-block partial stored to partials[block][128] (no global atomics).
__global__ __launch_bounds__(256) void k_main(
    const float* __restrict__ X, const short* __restrict__ w1frag,
    const float* __restrict__ b1, const float* __restrict__ wdeg,
    float* __restrict__ partials, int nNodes) {
  __shared__ short w1s[16384];  // 32 KiB: [(ct*4+ks)*64 + lane][8]
  __shared__ float sred[128];

  int tid = threadIdx.x;
  {
    const f32x4* src = reinterpret_cast<const f32x4*>(w1frag);
    f32x4* dst = reinterpret_cast<f32x4*>(w1s);
#pragma unroll
    for (int i = 0; i < 8; ++i) dst[tid + i * 256] = src[tid + i * 256];
  }
  if (tid < 128) sred[tid] = 0.f;
  __syncthreads();

  int lane = tid & 63, wave = tid >> 6;
  int rA = lane & 15;
  int kA = (lane >> 4) * 8;

  float b1r[8];
#pragma unroll
  for (int ct = 0; ct < 8; ++ct) b1r[ct] = b1[ct * 16 + rA];

  float sl[8] = {0, 0, 0, 0, 0, 0, 0, 0};

  int gw = blockIdx.x * 4 + wave;
  int nw = gridDim.x * 4;
  int nChunks = (nNodes + 15) >> 4;

  for (int c = gw; c < nChunks; c += nw) {
    int row0 = c << 4;
    int rowA = row0 + rA;
    if (rowA > nNodes - 1) rowA = nNodes - 1;
    const float* xp = X + (size_t)rowA * 128 + kA;

    f32x4 xv[8];
#pragma unroll
    for (int ks = 0; ks < 4; ++ks) {
      xv[2 * ks]     = *reinterpret_cast<const f32x4*>(xp + ks * 32);
      xv[2 * ks + 1] = *reinterpret_cast<const f32x4*>(xp + ks * 32 + 4);
    }

    f32x4 acc[8];
#pragma unroll
    for (int ct = 0; ct < 8; ++ct) acc[ct] = f32x4{0.f, 0.f, 0.f, 0.f};

#pragma unroll
    for (int ks = 0; ks < 4; ++ks) {
      short8 a;
#pragma unroll
      for (int e = 0; e < 4; ++e) a[e] = to_bf16s(xv[2 * ks][e]);
#pragma unroll
      for (int e = 0; e < 4; ++e) a[4 + e] = to_bf16s(xv[2 * ks + 1][e]);
#pragma unroll
      for (int ct = 0; ct < 8; ++ct) {
        short8 bfr = *reinterpret_cast<const short8*>(
            &w1s[((ct * 4 + ks) * 64 + lane) * 8]);
        acc[ct] = __builtin_amdgcn_mfma_f32_16x16x32_bf16(a, bfr, acc[ct], 0, 0, 0);
      }
    }

#pragma unroll
    for (int r = 0; r < 4; ++r) {
      int row = row0 + (lane >> 4) * 4 + r;
      float w = (row < nNodes) ? wdeg[row] : 0.0f;
#pragma unroll
      for (int ct = 0; ct < 8; ++ct) {
        float t = acc[ct][r] + b1r[ct];
        sl[ct] += w * fmaxf(t, 0.f);
      }
    }
  }

#pragma unroll
  for (int ct = 0; ct < 8; ++ct) {
    float v = sl[ct];
    v += __shfl_xor(v, 16);
    v += __shfl_xor(v, 32);
    if ((lane >> 4) == 0) atomicAdd(&sred[ct * 16 + rA], v);
  }
  __syncthreads();
  if (tid < 128) partials[(size_t)blockIdx.x * 128 + tid] = sred[tid];
}

// ---------------------------------------------------------------------------
// Reduce partials[B][128] -> sv; out = ((sv@W2 + (N+E)*b2)/N) @ Wp + bp
__global__ __launch_bounds__(256) void k_final(
    const float* __restrict__ partials, int B, const float* __restrict__ W2,
    const float* __restrict__ b2, const float* __restrict__ Wp,
    const float* __restrict__ bp, float* __restrict__ out,
    float totalW, float invN) {
  __shared__ float red[256];
  __shared__ float sv[128];
  __shared__ float pooled[128];
  int t = threadIdx.x;  // 256 threads
  {
    int col = t & 127, half = t >> 7;
    int r0 = half ? (B >> 1) : 0;
    int r1 = half ? B : (B >> 1);
    float s = 0.f;
    for (int r = r0; r < r1; ++r) s += partials[(size_t)r * 128 + col];
    red[t] = s;
  }
  __syncthreads();
  if (t < 128) sv[t] = red[t] + red[t + 128];
  __syncthreads();
  if (t < 128) {
    float acc = totalW * b2[t];
    for (int k = 0; k < 128; ++k) acc += sv[k] * W2[k * 128 + t];
    pooled[t] = acc * invN;
  }
  __syncthreads();
  if (t < 64) {
    float o = 0.f;
    for (int j = 0; j < 128; ++j) o += pooled[j] * Wp[j * 64 + t];
    out[t] = o + bp[t];
  }
}

// ---------------------------------------------------------------------------
extern "C" void kernel_launch(void* const* d_in, const int* in_sizes, int n_in,
                              void* d_out, int out_size, void* d_ws, size_t ws_size,
                              hipStream_t stream) {
  const float* X  = (const float*)d_in[0];
  const int*   ei = (const int*)d_in[1];
  const float* W1 = (const float*)d_in[2];
  const float* b1 = (const float*)d_in[3];
  const float* W2 = (const float*)d_in[4];
  const float* b2 = (const float*)d_in[5];
  const float* Wp = (const float*)d_in[6];
  const float* bp = (const float*)d_in[7];

  int N = in_sizes[0] / 128;
  int E = in_sizes[1] / 2;
  int nw = (N + 3) >> 2;
  const int MAIN_BLOCKS = 1024;

  // fixed-region sizes (256B-aligned)
  size_t spillB = ((size_t)nw * 4 * 4 + 255) & ~(size_t)255;   // u32 per node
  size_t wdegB  = ((size_t)nw * 4 * 4 + 255) & ~(size_t)255;   // f32 per node
  size_t fragB  = (16384 * 2 + 255) & ~(size_t)255;
  size_t partB  = ((size_t)MAIN_BLOCKS * 128 * 4 + 255) & ~(size_t)255;
  size_t fixed  = spillB + wdegB + fragB + partB + 256;

  int B1 = 0;  // number of private LDS-histogram blocks (0 => atomic fallback)
  if (nw <= HWORDS && ws_size > fixed) {
    size_t rem = ws_size - fixed;
    size_t b = rem / ((size_t)HWORDS * 4);
    B1 = (b > 128) ? 128 : (int)b;
  }

  char* p = (char*)d_ws;
  unsigned* priv  = (unsigned*)p;                 p += (size_t)B1 * HWORDS * 4;
  p = (char*)(((uintptr_t)p + 255) & ~(uintptr_t)255);
  unsigned* spill = (unsigned*)p;                 p += spillB;
  float*    wdeg  = (float*)p;                    p += wdegB;
  short*    frag  = (short*)p;                    p += fragB;
  float*    parts = (float*)p;

  // zero spill/deg accumulator (harness does not re-poison between replays)
  hipMemsetAsync(spill, 0, (size_t)nw * 4 * 4, stream);

  if (B1 > 0)
    k_h1<<<B1, 1024, 0, stream>>>(ei, priv, spill, E);
  else
    k_hist_fb<<<2048, 256, 0, stream>>>(ei, spill, E);

  int midBlocks = 64 + (nw + 255) / 256;
  k_mid<<<midBlocks, 256, 0, stream>>>(W1, frag, priv, spill, wdeg, N, B1);
  k_main<<<MAIN_BLOCKS, 256, 0, stream>>>(X, frag, b1, wdeg, parts, N);
  k_final<<<1, 256, 0, stream>>>(parts, MAIN_BLOCKS, W2, b2, Wp, bp,
                                 (float*)d_out, (float)N + (float)E,
                                 1.0f / (float)N);
}

// Round 4
// 62.434 us; speedup vs baseline: 2.9212x; 2.9212x over previous
//
#include <hip/hip_runtime.h>
#include <hip/hip_bf16.h>
#include <stdint.h>

typedef __attribute__((ext_vector_type(8))) short short8;
typedef __attribute__((ext_vector_type(4))) float f32x4;
typedef __attribute__((ext_vector_type(4))) int i32x4;

#define HWORDS 25600  // u32 words per private histogram (covers N <= 102400 as u8)

static __device__ __forceinline__ short to_bf16s(float f) {
  __hip_bfloat16 h = __float2bfloat16(f);
  return __builtin_bit_cast(short, h);
}

// ---------------------------------------------------------------------------
// Histogram of src = edge_index[0] (dst is algebraically unused: the final
// mean over all nodes collapses segment_sum to sum_e h[src[e]]).
// Per-block FULL-RANGE u8 histogram in LDS (100KB) -> zero global atomics on
// the per-edge path. Each block stores its private histogram; k_mid merges.
__global__ __launch_bounds__(1024) void k_h1(const int* __restrict__ e,
                                             unsigned* __restrict__ priv,
                                             unsigned* __restrict__ spill,
                                             int E) {
  __shared__ unsigned cnt[HWORDS];
  __shared__ int is64s;
  int tid = threadIdx.x;
  if (tid < 64) {  // layout detect: int64 -> high dwords all zero (LE)
    unsigned long long b = __ballot(e[2 * tid + 1] == 0);
    if (tid == 0) is64s = (__popcll(b) > 32) ? 1 : 0;
  }
  for (int j = tid; j < HWORDS; j += 1024) cnt[j] = 0u;
  __syncthreads();
  int is64 = is64s;

  int nq = E >> 2;
  int stride = gridDim.x * 1024;
  for (int q = blockIdx.x * 1024 + tid; q < nq; q += stride) {
    i32x4 v;
    if (is64) {
      i32x4 a = *reinterpret_cast<const i32x4*>(e + 8 * (size_t)q);
      i32x4 b = *reinterpret_cast<const i32x4*>(e + 8 * (size_t)q + 4);
      v = i32x4{a[0], a[2], b[0], b[2]};
    } else {
      v = *reinterpret_cast<const i32x4*>(e + 4 * (size_t)q);
    }
#pragma unroll
    for (int k = 0; k < 4; ++k) {
      unsigned n = (unsigned)v[k];
      unsigned sh = (n & 3u) * 8u;
      unsigned old = atomicAdd(&cnt[n >> 2], 1u << sh);
      if (((old >> sh) & 0xFFu) == 0xFFu) {  // rare u8 saturation: back out
        atomicSub(&cnt[n >> 2], 1u << sh);
        atomicAdd(&spill[n], 1u);
      }
    }
  }
  int tail = E & 3;
  if (blockIdx.x == 0 && tid < tail) {
    int idx = E - tail + tid;
    unsigned n = (unsigned)(is64 ? e[2 * idx] : e[idx]);
    unsigned sh = (n & 3u) * 8u;
    unsigned old = atomicAdd(&cnt[n >> 2], 1u << sh);
    if (((old >> sh) & 0xFFu) == 0xFFu) {
      atomicSub(&cnt[n >> 2], 1u << sh);
      atomicAdd(&spill[n], 1u);
    }
  }
  __syncthreads();
  unsigned* dst = priv + (size_t)blockIdx.x * HWORDS;
  for (int j = tid; j < HWORDS; j += 1024) dst[j] = cnt[j];
}

// Fallback when ws too small: device-atomic histogram into spill.
__global__ __launch_bounds__(256) void k_hist_fb(const int* __restrict__ e,
                                                 unsigned* __restrict__ deg, int E) {
  __shared__ int is64s;
  int tid = threadIdx.x;
  if (tid < 64) {
    unsigned long long b = __ballot(e[2 * tid + 1] == 0);
    if (tid == 0) is64s = (__popcll(b) > 32) ? 1 : 0;
  }
  __syncthreads();
  int is64 = is64s;
  int stride = gridDim.x * blockDim.x;
  for (int i = blockIdx.x * blockDim.x + tid; i < E; i += stride)
    atomicAdd(&deg[is64 ? (unsigned)e[2 * i] : (unsigned)e[i]], 1u);
}

// ---------------------------------------------------------------------------
// Blocks [0,64): W1 (f32 [128][128], h=x@W1) -> bf16 B-fragments for
//   mfma_f32_16x16x32_bf16. slot=(ct*4+ks)*64+lane holds 8 bf16:
//   col = ct*16+(lane&15), k = ks*32+(lane>>4)*8+e.
// Blocks [64,..): merge B1 private u8 histograms -> wdeg = 1 + deg (+spill).
// Word-sum trick: per-byte totals = true degree < 256 -> no cross-byte carry.
__global__ __launch_bounds__(256) void k_mid(const float* __restrict__ W1,
                                             short* __restrict__ frag,
                                             const unsigned* __restrict__ priv,
                                             const unsigned* __restrict__ spill,
                                             float* __restrict__ wdeg,
                                             int N, int B1) {
  int b = blockIdx.x;
  if (b < 64) {
    int idx = b * 256 + threadIdx.x;  // k*128 + col
    int k = idx >> 7, col = idx & 127;
    int ct = col >> 4, ks = k >> 5, lh = (k >> 3) & 3, e = k & 7;
    int lane = lh * 16 + (col & 15);
    frag[((ct * 4 + ks) * 64 + lane) * 8 + e] = to_bf16s(W1[idx]);
  } else {
    int w = (b - 64) * 256 + threadIdx.x;  // word id = 4 nodes
    int nw = (N + 3) >> 2;
    if (w < nw) {
      unsigned s = 0;
      for (int c = 0; c < B1; ++c) s += priv[(size_t)c * HWORDS + w];
      int n0 = w << 2;
      f32x4 o;
      o[0] = 1.0f + (float)(s & 0xFFu) + (float)spill[n0 + 0];
      o[1] = 1.0f + (float)((s >> 8) & 0xFFu) + (float)spill[n0 + 1];
      o[2] = 1.0f + (float)((s >> 16) & 0xFFu) + (float)spill[n0 + 2];
      o[3] = 1.0f + (float)(s >> 24) + (float)spill[n0 + 3];
      *reinterpret_cast<f32x4*>(wdeg + n0) = o;
    }
  }
}

// ---------------------------------------------------------------------------
// Main: s[j] = sum_n wdeg[n] * relu( (X@W1)[n][j] + b1[j] ),  j = 0..127.
// Per-block partial stored to partials[block][128] (no global atomics).
__global__ __launch_bounds__(256) void k_main(
    const float* __restrict__ X, const short* __restrict__ w1frag,
    const float* __restrict__ b1, const float* __restrict__ wdeg,
    float* __restrict__ partials, int nNodes) {
  __shared__ short w1s[16384];  // 32 KiB: [(ct*4+ks)*64 + lane][8]
  __shared__ float sred[128];

  int tid = threadIdx.x;
  {
    const f32x4* src = reinterpret_cast<const f32x4*>(w1frag);
    f32x4* dst = reinterpret_cast<f32x4*>(w1s);
#pragma unroll
    for (int i = 0; i < 8; ++i) dst[tid + i * 256] = src[tid + i * 256];
  }
  if (tid < 128) sred[tid] = 0.f;
  __syncthreads();

  int lane = tid & 63, wave = tid >> 6;
  int rA = lane & 15;
  int kA = (lane >> 4) * 8;

  float b1r[8];
#pragma unroll
  for (int ct = 0; ct < 8; ++ct) b1r[ct] = b1[ct * 16 + rA];

  float sl[8] = {0, 0, 0, 0, 0, 0, 0, 0};

  int gw = blockIdx.x * 4 + wave;
  int nw = gridDim.x * 4;
  int nChunks = (nNodes + 15) >> 4;

  for (int c = gw; c < nChunks; c += nw) {
    int row0 = c << 4;
    int rowA = row0 + rA;
    if (rowA > nNodes - 1) rowA = nNodes - 1;
    const float* xp = X + (size_t)rowA * 128 + kA;

    f32x4 xv[8];
#pragma unroll
    for (int ks = 0; ks < 4; ++ks) {
      xv[2 * ks]     = *reinterpret_cast<const f32x4*>(xp + ks * 32);
      xv[2 * ks + 1] = *reinterpret_cast<const f32x4*>(xp + ks * 32 + 4);
    }

    f32x4 acc[8];
#pragma unroll
    for (int ct = 0; ct < 8; ++ct) acc[ct] = f32x4{0.f, 0.f, 0.f, 0.f};

#pragma unroll
    for (int ks = 0; ks < 4; ++ks) {
      short8 a;
#pragma unroll
      for (int e = 0; e < 4; ++e) a[e] = to_bf16s(xv[2 * ks][e]);
#pragma unroll
      for (int e = 0; e < 4; ++e) a[4 + e] = to_bf16s(xv[2 * ks + 1][e]);
#pragma unroll
      for (int ct = 0; ct < 8; ++ct) {
        short8 bfr = *reinterpret_cast<const short8*>(
            &w1s[((ct * 4 + ks) * 64 + lane) * 8]);
        acc[ct] = __builtin_amdgcn_mfma_f32_16x16x32_bf16(a, bfr, acc[ct], 0, 0, 0);
      }
    }

#pragma unroll
    for (int r = 0; r < 4; ++r) {
      int row = row0 + (lane >> 4) * 4 + r;
      float w = (row < nNodes) ? wdeg[row] : 0.0f;
#pragma unroll
      for (int ct = 0; ct < 8; ++ct) {
        float t = acc[ct][r] + b1r[ct];
        sl[ct] += w * fmaxf(t, 0.f);
      }
    }
  }

#pragma unroll
  for (int ct = 0; ct < 8; ++ct) {
    float v = sl[ct];
    v += __shfl_xor(v, 16);
    v += __shfl_xor(v, 32);
    if ((lane >> 4) == 0) atomicAdd(&sred[ct * 16 + rA], v);
  }
  __syncthreads();
  if (tid < 128) partials[(size_t)blockIdx.x * 128 + tid] = sred[tid];
}

// ---------------------------------------------------------------------------
// Stage-1 tree reduce: block b sums partials rows [b*rp, (b+1)*rp) -> red[b].
__global__ __launch_bounds__(256) void k_red(const float* __restrict__ partials,
                                             float* __restrict__ red, int rp) {
  __shared__ float buf[256];
  int t = threadIdx.x;
  int col = t & 127, half = t >> 7;
  int r0 = blockIdx.x * rp + half * (rp >> 1);
  float s = 0.f;
  for (int r = 0; r < (rp >> 1); ++r)
    s += partials[(size_t)(r0 + r) * 128 + col];
  buf[t] = s;
  __syncthreads();
  if (t < 128) red[(size_t)blockIdx.x * 128 + t] = buf[t] + buf[t + 128];
}

// ---------------------------------------------------------------------------
// Reduce red[B][128] -> sv; out = ((sv@W2 + (N+E)*b2)/N) @ Wp + bp.
// 1024 threads; matmuls are k-sliced (16 FMAs/thread) + LDS tree.
__global__ __launch_bounds__(1024) void k_final(
    const float* __restrict__ red, int B, const float* __restrict__ W2,
    const float* __restrict__ b2, const float* __restrict__ Wp,
    const float* __restrict__ bp, float* __restrict__ out,
    float totalW, float invN) {
  __shared__ float acc8[8][128];
  __shared__ float sv[128];
  __shared__ float pooled[128];
  int t = threadIdx.x;
  int col = t & 127, sl = t >> 7;  // 8 slices x 128 cols

  {  // reduce B rows, slice-strided
    float s = 0.f;
    for (int r = sl; r < B; r += 8) s += red[(size_t)r * 128 + col];
    acc8[sl][col] = s;
  }
  __syncthreads();
  if (t < 128) {
    float v = 0.f;
#pragma unroll
    for (int i = 0; i < 8; ++i) v += acc8[i][t];
    sv[t] = v;
  }
  __syncthreads();
  {  // pooled = (sv @ W2 + totalW*b2) * invN ; thread sums k-slice of 16
    float a = 0.f;
#pragma unroll
    for (int kk = 0; kk < 16; ++kk) {
      int k = sl * 16 + kk;
      a += sv[k] * W2[k * 128 + col];
    }
    acc8[sl][col] = a;
  }
  __syncthreads();
  if (t < 128) {
    float v = totalW * b2[t];
#pragma unroll
    for (int i = 0; i < 8; ++i) v += acc8[i][t];
    pooled[t] = v * invN;
  }
  __syncthreads();
  if (t < 512) {  // out = pooled @ Wp + bp ; 64 outs x 8 k-slices
    int o = t & 63, s2 = t >> 6;
    float a = 0.f;
#pragma unroll
    for (int kk = 0; kk < 16; ++kk) {
      int k = s2 * 16 + kk;
      a += pooled[k] * Wp[k * 64 + o];
    }
    acc8[s2][o] = a;
  }
  __syncthreads();
  if (t < 64) {
    float v = bp[t];
#pragma unroll
    for (int i = 0; i < 8; ++i) v += acc8[i][t];
    out[t] = v;
  }
}

// ---------------------------------------------------------------------------
extern "C" void kernel_launch(void* const* d_in, const int* in_sizes, int n_in,
                              void* d_out, int out_size, void* d_ws, size_t ws_size,
                              hipStream_t stream) {
  const float* X  = (const float*)d_in[0];
  const int*   ei = (const int*)d_in[1];
  const float* W1 = (const float*)d_in[2];
  const float* b1 = (const float*)d_in[3];
  const float* W2 = (const float*)d_in[4];
  const float* b2 = (const float*)d_in[5];
  const float* Wp = (const float*)d_in[6];
  const float* bp = (const float*)d_in[7];

  int N = in_sizes[0] / 128;
  int E = in_sizes[1] / 2;
  int nw = (N + 3) >> 2;
  const int MAIN_BLOCKS = 1024;
  const int RED_BLOCKS = 64;

  // fixed-region sizes (256B-aligned)
  size_t spillB = ((size_t)nw * 4 * 4 + 255) & ~(size_t)255;   // u32 per node
  size_t wdegB  = ((size_t)nw * 4 * 4 + 255) & ~(size_t)255;   // f32 per node
  size_t fragB  = (16384 * 2 + 255) & ~(size_t)255;
  size_t partB  = ((size_t)MAIN_BLOCKS * 128 * 4 + 255) & ~(size_t)255;
  size_t redB   = ((size_t)RED_BLOCKS * 128 * 4 + 255) & ~(size_t)255;
  size_t fixed  = spillB + wdegB + fragB + partB + redB + 256;

  int B1 = 0;  // number of private LDS-histogram blocks (0 => atomic fallback)
  if (nw <= HWORDS && ws_size > fixed) {
    size_t rem = ws_size - fixed;
    size_t b = rem / ((size_t)HWORDS * 4);
    B1 = (b > 128) ? 128 : (int)b;
  }

  char* p = (char*)d_ws;
  unsigned* priv  = (unsigned*)p;                 p += (size_t)B1 * HWORDS * 4;
  p = (char*)(((uintptr_t)p + 255) & ~(uintptr_t)255);
  unsigned* spill = (unsigned*)p;                 p += spillB;
  float*    wdeg  = (float*)p;                    p += wdegB;
  short*    frag  = (short*)p;                    p += fragB;
  float*    parts = (float*)p;                    p += partB;
  float*    red   = (float*)p;

  // zero spill/deg accumulator (harness does not re-poison between replays)
  hipMemsetAsync(spill, 0, (size_t)nw * 4 * 4, stream);

  if (B1 > 0)
    k_h1<<<B1, 1024, 0, stream>>>(ei, priv, spill, E);
  else
    k_hist_fb<<<2048, 256, 0, stream>>>(ei, spill, E);

  int midBlocks = 64 + (nw + 255) / 256;
  k_mid<<<midBlocks, 256, 0, stream>>>(W1, frag, priv, spill, wdeg, N, B1);
  k_main<<<MAIN_BLOCKS, 256, 0, stream>>>(X, frag, b1, wdeg, parts, N);
  k_red<<<RED_BLOCKS, 256, 0, stream>>>(parts, red, MAIN_BLOCKS / RED_BLOCKS);
  k_final<<<1, 1024, 0, stream>>>(red, RED_BLOCKS, W2, b2, Wp, bp,
                                  (float*)d_out, (float)N + (float)E,
                                  1.0f / (float)N);
}

// Round 5
// 49.270 us; speedup vs baseline: 3.7017x; 1.2672x over previous
//
#include <hip/hip_runtime.h>
#include <hip/hip_bf16.h>
#include <stdint.h>

typedef __attribute__((ext_vector_type(8))) short short8;
typedef __attribute__((ext_vector_type(4))) float f32x4;
typedef __attribute__((ext_vector_type(4))) int i32x4;

#define HWORDS 25600  // u32 words per private histogram (covers N <= 102400 as u8)

static __device__ __forceinline__ short to_bf16s(float f) {
  __hip_bfloat16 h = __float2bfloat16(f);
  return __builtin_bit_cast(short, h);
}

// ---------------------------------------------------------------------------
// Blocks [0,64): W1 (f32 [128][128], h=x@W1) -> bf16 B-fragments for
//   mfma_f32_16x16x32_bf16. slot=(ct*4+ks)*64+lane holds 8 bf16:
//   col = ct*16+(lane&15), k = ks*32+(lane>>4)*8+e.
// Blocks [64,..): zero the spill array (replaces hipMemsetAsync, whose rocclr
//   fill kernel ran latency-bound at ~39us).
__global__ __launch_bounds__(256) void k_prep(const float* __restrict__ W1,
                                              short* __restrict__ frag,
                                              f32x4* __restrict__ spillv,
                                              int spillWords4) {
  int b = blockIdx.x;
  if (b < 64) {
    int idx = b * 256 + threadIdx.x;  // k*128 + col
    int k = idx >> 7, col = idx & 127;
    int ct = col >> 4, ks = k >> 5, lh = (k >> 3) & 3, e = k & 7;
    int lane = lh * 16 + (col & 15);
    frag[((ct * 4 + ks) * 64 + lane) * 8 + e] = to_bf16s(W1[idx]);
  } else {
    int w4 = (b - 64) * 256 + threadIdx.x;
    if (w4 < spillWords4) spillv[w4] = f32x4{0.f, 0.f, 0.f, 0.f};
  }
}

// ---------------------------------------------------------------------------
// Histogram of src = edge_index[0] (dst is algebraically unused: the final
// mean over all nodes collapses segment_sum to sum_e h[src[e]]).
// Per-block FULL-RANGE u8 histogram in LDS (100KB) -> zero global atomics on
// the per-edge path. Each block stores its private histogram; k_merge merges.
__global__ __launch_bounds__(1024) void k_h1(const int* __restrict__ e,
                                             unsigned* __restrict__ priv,
                                             unsigned* __restrict__ spill,
                                             int E) {
  __shared__ unsigned cnt[HWORDS];
  __shared__ int is64s;
  int tid = threadIdx.x;
  if (tid < 64) {  // layout detect: int64 -> high dwords all zero (LE)
    unsigned long long b = __ballot(e[2 * tid + 1] == 0);
    if (tid == 0) is64s = (__popcll(b) > 32) ? 1 : 0;
  }
  for (int j = tid; j < HWORDS; j += 1024) cnt[j] = 0u;
  __syncthreads();
  int is64 = is64s;

  int nq = E >> 2;
  int stride = gridDim.x * 1024;
  for (int q = blockIdx.x * 1024 + tid; q < nq; q += stride) {
    i32x4 v;
    if (is64) {
      i32x4 a = *reinterpret_cast<const i32x4*>(e + 8 * (size_t)q);
      i32x4 b = *reinterpret_cast<const i32x4*>(e + 8 * (size_t)q + 4);
      v = i32x4{a[0], a[2], b[0], b[2]};
    } else {
      v = *reinterpret_cast<const i32x4*>(e + 4 * (size_t)q);
    }
#pragma unroll
    for (int k = 0; k < 4; ++k) {
      unsigned n = (unsigned)v[k];
      unsigned sh = (n & 3u) * 8u;
      unsigned old = atomicAdd(&cnt[n >> 2], 1u << sh);
      if (((old >> sh) & 0xFFu) == 0xFFu) {  // rare u8 saturation: back out
        atomicSub(&cnt[n >> 2], 1u << sh);
        atomicAdd(&spill[n], 1u);
      }
    }
  }
  int tail = E & 3;
  if (blockIdx.x == 0 && tid < tail) {
    int idx = E - tail + tid;
    unsigned n = (unsigned)(is64 ? e[2 * idx] : e[idx]);
    unsigned sh = (n & 3u) * 8u;
    unsigned old = atomicAdd(&cnt[n >> 2], 1u << sh);
    if (((old >> sh) & 0xFFu) == 0xFFu) {
      atomicSub(&cnt[n >> 2], 1u << sh);
      atomicAdd(&spill[n], 1u);
    }
  }
  __syncthreads();
  unsigned* dst = priv + (size_t)blockIdx.x * HWORDS;
  for (int j = tid; j < HWORDS; j += 1024) dst[j] = cnt[j];
}

// Fallback when ws too small: device-atomic histogram into spill.
__global__ __launch_bounds__(256) void k_hist_fb(const int* __restrict__ e,
                                                 unsigned* __restrict__ deg, int E) {
  __shared__ int is64s;
  int tid = threadIdx.x;
  if (tid < 64) {
    unsigned long long b = __ballot(e[2 * tid + 1] == 0);
    if (tid == 0) is64s = (__popcll(b) > 32) ? 1 : 0;
  }
  __syncthreads();
  int is64 = is64s;
  int stride = gridDim.x * blockDim.x;
  for (int i = blockIdx.x * blockDim.x + tid; i < E; i += stride)
    atomicAdd(&deg[is64 ? (unsigned)e[2 * i] : (unsigned)e[i]], 1u);
}

// ---------------------------------------------------------------------------
// Merge B1 private u8 histograms -> wdeg = 1 + deg (+spill).
// Word-sum trick: per-byte totals = true degree < 256 -> no cross-byte carry.
__global__ __launch_bounds__(256) void k_merge(const unsigned* __restrict__ priv,
                                               const unsigned* __restrict__ spill,
                                               float* __restrict__ wdeg,
                                               int N, int B1) {
  int w = blockIdx.x * 256 + threadIdx.x;  // word id = 4 nodes
  int nw = (N + 3) >> 2;
  if (w >= nw) return;
  unsigned s = 0;
#pragma unroll 8
  for (int c = 0; c < B1; ++c) s += priv[(size_t)c * HWORDS + w];
  int n0 = w << 2;
  f32x4 o;
  o[0] = 1.0f + (float)(s & 0xFFu) + (float)spill[n0 + 0];
  o[1] = 1.0f + (float)((s >> 8) & 0xFFu) + (float)spill[n0 + 1];
  o[2] = 1.0f + (float)((s >> 16) & 0xFFu) + (float)spill[n0 + 2];
  o[3] = 1.0f + (float)(s >> 24) + (float)spill[n0 + 3];
  *reinterpret_cast<f32x4*>(wdeg + n0) = o;
}

// ---------------------------------------------------------------------------
// Main: s[j] = sum_n wdeg[n] * relu( (X@W1)[n][j] + b1[j] ),  j = 0..127.
// Per-block partial stored to partials[block][128] (no global atomics).
__global__ __launch_bounds__(256) void k_main(
    const float* __restrict__ X, const short* __restrict__ w1frag,
    const float* __restrict__ b1, const float* __restrict__ wdeg,
    float* __restrict__ partials, int nNodes) {
  __shared__ short w1s[16384];  // 32 KiB: [(ct*4+ks)*64 + lane][8]
  __shared__ float sred[128];

  int tid = threadIdx.x;
  {
    const f32x4* src = reinterpret_cast<const f32x4*>(w1frag);
    f32x4* dst = reinterpret_cast<f32x4*>(w1s);
#pragma unroll
    for (int i = 0; i < 8; ++i) dst[tid + i * 256] = src[tid + i * 256];
  }
  if (tid < 128) sred[tid] = 0.f;
  __syncthreads();

  int lane = tid & 63, wave = tid >> 6;
  int rA = lane & 15;
  int kA = (lane >> 4) * 8;

  float b1r[8];
#pragma unroll
  for (int ct = 0; ct < 8; ++ct) b1r[ct] = b1[ct * 16 + rA];

  float sl[8] = {0, 0, 0, 0, 0, 0, 0, 0};

  int gw = blockIdx.x * 4 + wave;
  int nw = gridDim.x * 4;
  int nChunks = (nNodes + 15) >> 4;

  for (int c = gw; c < nChunks; c += nw) {
    int row0 = c << 4;
    int rowA = row0 + rA;
    if (rowA > nNodes - 1) rowA = nNodes - 1;
    const float* xp = X + (size_t)rowA * 128 + kA;

    f32x4 xv[8];
#pragma unroll
    for (int ks = 0; ks < 4; ++ks) {
      xv[2 * ks]     = *reinterpret_cast<const f32x4*>(xp + ks * 32);
      xv[2 * ks + 1] = *reinterpret_cast<const f32x4*>(xp + ks * 32 + 4);
    }

    f32x4 acc[8];
#pragma unroll
    for (int ct = 0; ct < 8; ++ct) acc[ct] = f32x4{0.f, 0.f, 0.f, 0.f};

#pragma unroll
    for (int ks = 0; ks < 4; ++ks) {
      short8 a;
#pragma unroll
      for (int e = 0; e < 4; ++e) a[e] = to_bf16s(xv[2 * ks][e]);
#pragma unroll
      for (int e = 0; e < 4; ++e) a[4 + e] = to_bf16s(xv[2 * ks + 1][e]);
#pragma unroll
      for (int ct = 0; ct < 8; ++ct) {
        short8 bfr = *reinterpret_cast<const short8*>(
            &w1s[((ct * 4 + ks) * 64 + lane) * 8]);
        acc[ct] = __builtin_amdgcn_mfma_f32_16x16x32_bf16(a, bfr, acc[ct], 0, 0, 0);
      }
    }

#pragma unroll
    for (int r = 0; r < 4; ++r) {
      int row = row0 + (lane >> 4) * 4 + r;
      float w = (row < nNodes) ? wdeg[row] : 0.0f;
#pragma unroll
      for (int ct = 0; ct < 8; ++ct) {
        float t = acc[ct][r] + b1r[ct];
        sl[ct] += w * fmaxf(t, 0.f);
      }
    }
  }

#pragma unroll
  for (int ct = 0; ct < 8; ++ct) {
    float v = sl[ct];
    v += __shfl_xor(v, 16);
    v += __shfl_xor(v, 32);
    if ((lane >> 4) == 0) atomicAdd(&sred[ct * 16 + rA], v);
  }
  __syncthreads();
  if (tid < 128) partials[(size_t)blockIdx.x * 128 + tid] = sred[tid];
}

// ---------------------------------------------------------------------------
// Fused reduce + epilogue (single block, 1024 threads):
//   sv = sum_rows partials[B][128]
//   pooled = (sv@W2 + (N+E)*b2)/N ; out = pooled@Wp + bp
__global__ __launch_bounds__(1024) void k_final(
    const float* __restrict__ partials, int B, const float* __restrict__ W2,
    const float* __restrict__ b2, const float* __restrict__ Wp,
    const float* __restrict__ bp, float* __restrict__ out,
    float totalW, float invN) {
  __shared__ float accs[32][128];  // 16 KiB
  __shared__ float sv[128];
  __shared__ float pooled[128];
  int t = threadIdx.x;

  {  // phase A: 32 slices x 32 f32x4 column-groups over B rows
    int slc = t >> 5, cg = t & 31;
    f32x4 s = f32x4{0.f, 0.f, 0.f, 0.f};
    for (int r = slc; r < B; r += 32)
      s += *reinterpret_cast<const f32x4*>(partials + (size_t)r * 128 + cg * 4);
    *reinterpret_cast<f32x4*>(&accs[slc][cg * 4]) = s;
  }
  __syncthreads();
  if (t < 128) {
    float v = 0.f;
#pragma unroll
    for (int i = 0; i < 32; ++i) v += accs[i][t];
    sv[t] = v;
  }
  __syncthreads();
  {  // phase B: pooled = (sv@W2 + totalW*b2)*invN ; 8 k-slices x 128 cols
    int sl8 = t >> 7, col = t & 127;
    float a = 0.f;
#pragma unroll
    for (int kk = 0; kk < 16; ++kk) {
      int k = sl8 * 16 + kk;
      a += sv[k] * W2[k * 128 + col];
    }
    accs[sl8][col] = a;
  }
  __syncthreads();
  if (t < 128) {
    float v = totalW * b2[t];
#pragma unroll
    for (int i = 0; i < 8; ++i) v += accs[i][t];
    pooled[t] = v * invN;
  }
  __syncthreads();
  if (t < 512) {  // phase C: out = pooled@Wp + bp ; 64 outs x 8 k-slices
    int o = t & 63, s2 = t >> 6;
    float a = 0.f;
#pragma unroll
    for (int kk = 0; kk < 16; ++kk) {
      int k = s2 * 16 + kk;
      a += pooled[k] * Wp[k * 64 + o];
    }
    accs[s2][o] = a;
  }
  __syncthreads();
  if (t < 64) {
    float v = bp[t];
#pragma unroll
    for (int i = 0; i < 8; ++i) v += accs[i][t];
    out[t] = v;
  }
}

// ---------------------------------------------------------------------------
extern "C" void kernel_launch(void* const* d_in, const int* in_sizes, int n_in,
                              void* d_out, int out_size, void* d_ws, size_t ws_size,
                              hipStream_t stream) {
  const float* X  = (const float*)d_in[0];
  const int*   ei = (const int*)d_in[1];
  const float* W1 = (const float*)d_in[2];
  const float* b1 = (const float*)d_in[3];
  const float* W2 = (const float*)d_in[4];
  const float* b2 = (const float*)d_in[5];
  const float* Wp = (const float*)d_in[6];
  const float* bp = (const float*)d_in[7];

  int N = in_sizes[0] / 128;
  int E = in_sizes[1] / 2;
  int nw = (N + 3) >> 2;  // u32 words in histogram / spill
  const int MAIN_BLOCKS = 784;  // 3136 waves; 6250 chunks -> ~2 each (99.6% bal)

  // fixed-region sizes (256B-aligned)
  size_t spillB = ((size_t)nw * 4 * 4 + 255) & ~(size_t)255;   // u32 per node
  size_t wdegB  = ((size_t)nw * 4 * 4 + 255) & ~(size_t)255;   // f32 per node
  size_t fragB  = (16384 * 2 + 255) & ~(size_t)255;
  size_t partB  = ((size_t)MAIN_BLOCKS * 128 * 4 + 255) & ~(size_t)255;
  size_t fixed  = spillB + wdegB + fragB + partB + 256;

  int B1 = 0;  // number of private LDS-histogram blocks (0 => atomic fallback)
  if (nw <= HWORDS && ws_size > fixed) {
    size_t rem = ws_size - fixed;
    size_t b = rem / ((size_t)HWORDS * 4);
    B1 = (b > 128) ? 128 : (int)b;
  }

  char* p = (char*)d_ws;
  unsigned* priv  = (unsigned*)p;                 p += (size_t)B1 * HWORDS * 4;
  p = (char*)(((uintptr_t)p + 255) & ~(uintptr_t)255);
  unsigned* spill = (unsigned*)p;                 p += spillB;
  float*    wdeg  = (float*)p;                    p += wdegB;
  short*    frag  = (short*)p;                    p += fragB;
  float*    parts = (float*)p;

  // prep fragments + zero spill (our own wide fill; rocclr's fill was 39us)
  int spillWords4 = nw;  // nw u32-words4? spill has N u32 = nw*4; /4 per f32x4 = nw
  int zeroBlocks = (spillWords4 + 255) / 256;
  k_prep<<<64 + zeroBlocks, 256, 0, stream>>>(W1, frag, (f32x4*)spill, spillWords4);

  if (B1 > 0)
    k_h1<<<B1, 1024, 0, stream>>>(ei, priv, spill, E);
  else
    k_hist_fb<<<2048, 256, 0, stream>>>(ei, spill, E);

  k_merge<<<(nw + 255) / 256, 256, 0, stream>>>(priv, spill, wdeg, N, B1);
  k_main<<<MAIN_BLOCKS, 256, 0, stream>>>(X, frag, b1, wdeg, parts, N);
  k_final<<<1, 1024, 0, stream>>>(parts, MAIN_BLOCKS, W2, b2, Wp, bp,
                                  (float*)d_out, (float)N + (float)E,
                                  1.0f / (float)N);
}

// Round 6
// 36.653 us; speedup vs baseline: 4.9759x; 1.3442x over previous
//
#include <hip/hip_runtime.h>
#include <hip/hip_bf16.h>
#include <stdint.h>

typedef __attribute__((ext_vector_type(8))) short short8;
typedef __attribute__((ext_vector_type(4))) float f32x4;
typedef __attribute__((ext_vector_type(4))) int i32x4;

#define RANGE  51200   // nodes per LDS half-range (u16 counters -> 100KB)
#define RWORDS 25600   // u32 words per range histogram
#define NHIST  128     // hist blocks = 64 edge-slices x 2 ranges
#define NFRAG  16      // frag-prep blocks (16384 threads total)

static __device__ __forceinline__ short to_bf16s(float f) {
  __hip_bfloat16 h = __float2bfloat16(f);
  return __builtin_bit_cast(short, h);
}

// ---------------------------------------------------------------------------
// Fused: blocks [0,NFRAG) convert W1 -> bf16 MFMA B-fragments;
// blocks [NFRAG,..) build per-block u16 half-range histograms of
// src = edge_index[0] in LDS. dst is algebraically unused (the final mean
// over all nodes collapses segment_sum to sum_e h[src[e]]).
// u16 safety: each block sees <= ~15.6K edges < 65535 -> no overflow, no
// spill, no pre-zeroing, and fire-and-forget ds_add (no _rtn stall).
__global__ __launch_bounds__(1024) void k_histprep(
    const int* __restrict__ e, unsigned* __restrict__ priv,
    short* __restrict__ frag, const float* __restrict__ W1, int E) {
  __shared__ unsigned cnt[RWORDS];
  __shared__ int is64s;
  int b = blockIdx.x, tid = threadIdx.x;
  if (b < NFRAG) {
    int idx = b * 1024 + tid;  // k*128 + col
    int k = idx >> 7, col = idx & 127;
    int ct = col >> 4, ks = k >> 5, lh = (k >> 3) & 3, ee = k & 7;
    int lane = lh * 16 + (col & 15);
    frag[((ct * 4 + ks) * 64 + lane) * 8 + ee] = to_bf16s(W1[idx]);
    return;
  }
  int h = b - NFRAG;
  int r = h & 1, s = h >> 1;  // range, edge-slice
  if (tid < 64) {  // layout detect: int64 -> high dwords all zero (LE)
    unsigned long long bl = __ballot(e[2 * tid + 1] == 0);
    if (tid == 0) is64s = (__popcll(bl) > 32) ? 1 : 0;
  }
  for (int j = tid; j < RWORDS; j += 1024) cnt[j] = 0u;
  __syncthreads();
  int is64 = is64s;
  unsigned base = (unsigned)r * RANGE;
  int nq = E >> 2;
  int qlo = (int)((long long)s * nq / 64);
  int qhi = (int)((long long)(s + 1) * nq / 64);
  for (int q = qlo + tid; q < qhi; q += 1024) {
    i32x4 v;
    if (is64) {
      i32x4 a = *reinterpret_cast<const i32x4*>(e + 8 * (size_t)q);
      i32x4 bb = *reinterpret_cast<const i32x4*>(e + 8 * (size_t)q + 4);
      v = i32x4{a[0], a[2], bb[0], bb[2]};
    } else {
      v = *reinterpret_cast<const i32x4*>(e + 4 * (size_t)q);
    }
#pragma unroll
    for (int k = 0; k < 4; ++k) {
      unsigned loc = (unsigned)v[k] - base;
      if (loc < (unsigned)RANGE)
        atomicAdd(&cnt[loc >> 1], 1u << (16 * (loc & 1)));
    }
  }
  if (s == 0) {  // tail edges (E%4) handled once per range
    int tail = E & 3;
    if (tid < tail) {
      int idx = E - tail + tid;
      unsigned loc = (unsigned)(is64 ? e[2 * idx] : e[idx]) - base;
      if (loc < (unsigned)RANGE)
        atomicAdd(&cnt[loc >> 1], 1u << (16 * (loc & 1)));
    }
  }
  __syncthreads();
  unsigned* dst = priv + (size_t)h * RWORDS;
  for (int j = tid; j < RWORDS; j += 1024) dst[j] = cnt[j];
}

// ---------------------------------------------------------------------------
// Merge 64 u16 copies per range -> wdeg = 1 + deg. Unpack before summing
// (sums fit u32; deg < 2^24 so float exact).
__global__ __launch_bounds__(256) void k_mergewdeg(
    const unsigned* __restrict__ priv, float* __restrict__ wdeg, int N) {
  int g = blockIdx.x * 256 + threadIdx.x;  // word id across both ranges
  if (g >= 2 * RWORDS) return;
  int r = (g >= RWORDS) ? 1 : 0;
  int word = g - r * RWORDS;
  unsigned lo = 0, hi = 0;
  const unsigned* p = priv + (size_t)r * RWORDS + word;
#pragma unroll 8
  for (int s = 0; s < 64; ++s) {
    unsigned v = p[(size_t)s * 2 * RWORDS];
    lo += v & 0xFFFFu;
    hi += v >> 16;
  }
  int n0 = r * RANGE + word * 2;
  if (n0 < N) wdeg[n0] = 1.0f + (float)lo;
  if (n0 + 1 < N) wdeg[n0 + 1] = 1.0f + (float)hi;
}

// ---------------------------------------------------------------------------
// Main: s[j] = sum_n wdeg[n] * relu( (X@W1)[n][j] + b1[j] ), j = 0..127.
// 64-row chunks: block-cooperative COALESCED load of X (2KB/wave bursts),
// bf16-convert, XOR-swizzled LDS tile (kc ^= row&7 on 16B units; read side
// lands 2 lanes/bank = free), then per-wave MFMA from ds_read_b128.
__global__ __launch_bounds__(256) void k_main(
    const float* __restrict__ X, const short* __restrict__ w1frag,
    const float* __restrict__ b1, const float* __restrict__ wdeg,
    float* __restrict__ partials, int nNodes) {
  __shared__ short w1s[16384];  // 32KB W1 B-frags
  __shared__ short xs[8192];    // 16KB A-tile: 64 rows x 128 k, swizzled
  __shared__ float sred[128];

  int tid = threadIdx.x;
  {
    const f32x4* src = reinterpret_cast<const f32x4*>(w1frag);
    f32x4* dst = reinterpret_cast<f32x4*>(w1s);
#pragma unroll
    for (int i = 0; i < 8; ++i) dst[tid + i * 256] = src[tid + i * 256];
  }
  if (tid < 128) sred[tid] = 0.f;

  int lane = tid & 63, wave = tid >> 6;
  int rA = lane & 15;   // A-row in 16-row group / C-col low bits
  int kh = lane >> 4;   // k-offset group (0..3)

  float b1r[8];
#pragma unroll
  for (int ct = 0; ct < 8; ++ct) b1r[ct] = b1[ct * 16 + rA];

  float sl[8] = {0, 0, 0, 0, 0, 0, 0, 0};
  int nChunks = (nNodes + 63) >> 6;
  __syncthreads();

  for (int c = blockIdx.x; c < nChunks; c += gridDim.x) {
    int row0 = c << 6;
    // ---- stage: 64 rows x 512B, fully coalesced, -> swizzled bf16 LDS ----
#pragma unroll
    for (int p = 0; p < 4; ++p) {
      int j = p * 256 + tid;  // 16B-unit id = row*16 + kc
      int rl = j >> 4, kc = j & 15;
      int grow = row0 + rl;
      if (grow > nNodes - 1) grow = nNodes - 1;
      const f32x4* gp =
          reinterpret_cast<const f32x4*>(X + (size_t)grow * 128 + kc * 8);
      f32x4 lo = gp[0], hi = gp[1];
      short8 v;
#pragma unroll
      for (int ee = 0; ee < 4; ++ee) {
        v[ee] = to_bf16s(lo[ee]);
        v[4 + ee] = to_bf16s(hi[ee]);
      }
      int u = rl * 16 + (kc ^ (rl & 7));
      *reinterpret_cast<short8*>(&xs[u * 8]) = v;
    }
    __syncthreads();

    // ---- compute: wave w owns local rows [w*16, w*16+16) ----
    int rloc = wave * 16 + rA;
    f32x4 acc[8];
#pragma unroll
    for (int ct = 0; ct < 8; ++ct) acc[ct] = f32x4{0.f, 0.f, 0.f, 0.f};
#pragma unroll
    for (int ks = 0; ks < 4; ++ks) {
      int kc = ks * 4 + kh;
      int u = rloc * 16 + (kc ^ (rloc & 7));
      short8 a = *reinterpret_cast<const short8*>(&xs[u * 8]);
#pragma unroll
      for (int ct = 0; ct < 8; ++ct) {
        short8 bfr = *reinterpret_cast<const short8*>(
            &w1s[((ct * 4 + ks) * 64 + lane) * 8]);
        acc[ct] = __builtin_amdgcn_mfma_f32_16x16x32_bf16(a, bfr, acc[ct], 0, 0, 0);
      }
    }
    // ---- epilogue: C elem (ct,rr): row = row0+wave*16+kh*4+rr ----
#pragma unroll
    for (int rr = 0; rr < 4; ++rr) {
      int row = row0 + wave * 16 + kh * 4 + rr;
      float w = (row < nNodes) ? wdeg[row] : 0.0f;
#pragma unroll
      for (int ct = 0; ct < 8; ++ct)
        sl[ct] += w * fmaxf(acc[ct][rr] + b1r[ct], 0.f);
    }
    __syncthreads();  // protect xs before next stage
  }

#pragma unroll
  for (int ct = 0; ct < 8; ++ct) {
    float v = sl[ct];
    v += __shfl_xor(v, 16);
    v += __shfl_xor(v, 32);
    if (kh == 0) atomicAdd(&sred[ct * 16 + rA], v);
  }
  __syncthreads();
  if (tid < 128) partials[(size_t)blockIdx.x * 128 + tid] = sred[tid];
}

// ---------------------------------------------------------------------------
// Stage-1 tree reduce: block b sums partials rows [b*rp, (b+1)*rp) -> red[b].
__global__ __launch_bounds__(256) void k_red(const float* __restrict__ partials,
                                             float* __restrict__ red, int rp) {
  __shared__ float buf[256];
  int t = threadIdx.x;
  int col = t & 127, half = t >> 7;
  int r0 = blockIdx.x * rp + half * (rp >> 1);
  float s = 0.f;
  for (int r = 0; r < (rp >> 1); ++r)
    s += partials[(size_t)(r0 + r) * 128 + col];
  buf[t] = s;
  __syncthreads();
  if (t < 128) red[(size_t)blockIdx.x * 128 + t] = buf[t] + buf[t + 128];
}

// ---------------------------------------------------------------------------
// Reduce red[B][128] (B<=32) -> sv; out = ((sv@W2 + (N+E)*b2)/N)@Wp + bp.
__global__ __launch_bounds__(1024) void k_final(
    const float* __restrict__ red, int B, const float* __restrict__ W2,
    const float* __restrict__ b2, const float* __restrict__ Wp,
    const float* __restrict__ bp, float* __restrict__ out,
    float totalW, float invN) {
  __shared__ float accs[32][128];
  __shared__ float sv[128];
  __shared__ float pooled[128];
  int t = threadIdx.x;
  {  // phase A: 32 slices x 32 f32x4 col-groups (1 iter at B=32)
    int slc = t >> 5, cg = t & 31;
    f32x4 s = f32x4{0.f, 0.f, 0.f, 0.f};
    for (int r = slc; r < B; r += 32)
      s += *reinterpret_cast<const f32x4*>(red + (size_t)r * 128 + cg * 4);
    *reinterpret_cast<f32x4*>(&accs[slc][cg * 4]) = s;
  }
  __syncthreads();
  if (t < 128) {
    float v = 0.f;
#pragma unroll
    for (int i = 0; i < 32; ++i) v += accs[i][t];
    sv[t] = v;
  }
  __syncthreads();
  {  // pooled = (sv@W2 + totalW*b2)*invN ; 8 k-slices x 128 cols
    int sl8 = t >> 7, col = t & 127;
    float a = 0.f;
#pragma unroll
    for (int kk = 0; kk < 16; ++kk) {
      int k = sl8 * 16 + kk;
      a += sv[k] * W2[k * 128 + col];
    }
    accs[sl8][col] = a;
  }
  __syncthreads();
  if (t < 128) {
    float v = totalW * b2[t];
#pragma unroll
    for (int i = 0; i < 8; ++i) v += accs[i][t];
    pooled[t] = v * invN;
  }
  __syncthreads();
  if (t < 512) {  // out = pooled@Wp + bp ; 64 outs x 8 k-slices
    int o = t & 63, s2 = t >> 6;
    float a = 0.f;
#pragma unroll
    for (int kk = 0; kk < 16; ++kk) {
      int k = s2 * 16 + kk;
      a += pooled[k] * Wp[k * 64 + o];
    }
    accs[s2][o] = a;
  }
  __syncthreads();
  if (t < 64) {
    float v = bp[t];
#pragma unroll
    for (int i = 0; i < 8; ++i) v += accs[i][t];
    out[t] = v;
  }
}

// ---------------------------------------------------------------------------
// Fallback path (ws too small for private histograms): zero+atomic hist+cvt.
__global__ void k_zero(unsigned* __restrict__ p, int n) {
  int i = blockIdx.x * 256 + threadIdx.x;
  if (i < n) p[i] = 0u;
}
__global__ __launch_bounds__(256) void k_hist_fb(const int* __restrict__ e,
                                                 unsigned* __restrict__ deg,
                                                 int E) {
  __shared__ int is64s;
  int tid = threadIdx.x;
  if (tid < 64) {
    unsigned long long bl = __ballot(e[2 * tid + 1] == 0);
    if (tid == 0) is64s = (__popcll(bl) > 32) ? 1 : 0;
  }
  __syncthreads();
  int is64 = is64s;
  int stride = gridDim.x * blockDim.x;
  for (int i = blockIdx.x * blockDim.x + tid; i < E; i += stride)
    atomicAdd(&deg[is64 ? (unsigned)e[2 * i] : (unsigned)e[i]], 1u);
}
__global__ void k_cvt(const unsigned* __restrict__ deg,
                      float* __restrict__ wdeg, int N) {
  int i = blockIdx.x * 256 + threadIdx.x;
  if (i < N) wdeg[i] = 1.0f + (float)deg[i];
}

// ---------------------------------------------------------------------------
extern "C" void kernel_launch(void* const* d_in, const int* in_sizes, int n_in,
                              void* d_out, int out_size, void* d_ws, size_t ws_size,
                              hipStream_t stream) {
  const float* X  = (const float*)d_in[0];
  const int*   ei = (const int*)d_in[1];
  const float* W1 = (const float*)d_in[2];
  const float* b1 = (const float*)d_in[3];
  const float* W2 = (const float*)d_in[4];
  const float* b2 = (const float*)d_in[5];
  const float* Wp = (const float*)d_in[6];
  const float* bp = (const float*)d_in[7];

  int N = in_sizes[0] / 128;
  int E = in_sizes[1] / 2;
  const int MAIN_BLOCKS = 512;
  const int RED_BLOCKS = 32;

  size_t privB = (size_t)NHIST * RWORDS * 4;                  // 13.1 MB
  size_t fragB = (16384 * 2 + 255) & ~(size_t)255;
  size_t wdegB = ((size_t)N * 4 + 255) & ~(size_t)255;
  size_t degB  = wdegB;                                       // fallback only
  size_t partB = ((size_t)MAIN_BLOCKS * 128 * 4 + 255) & ~(size_t)255;
  size_t redB  = ((size_t)RED_BLOCKS * 128 * 4 + 255) & ~(size_t)255;

  bool fast = (N <= 2 * RANGE) &&
              (ws_size >= privB + fragB + wdegB + partB + redB + 512);

  char* p = (char*)d_ws;
  unsigned* priv = (unsigned*)p;
  if (fast) p += privB;
  p = (char*)(((uintptr_t)p + 255) & ~(uintptr_t)255);
  short* frag = (short*)p;    p += fragB;
  float* wdeg = (float*)p;    p += wdegB;
  unsigned* deg = (unsigned*)p;  // fallback dual-use region
  if (!fast) p += degB;
  float* parts = (float*)p;   p += partB;
  float* red = (float*)p;

  if (fast) {
    k_histprep<<<NFRAG + NHIST, 1024, 0, stream>>>(ei, priv, frag, W1, E);
    k_mergewdeg<<<(2 * RWORDS + 255) / 256, 256, 0, stream>>>(priv, wdeg, N);
  } else {
    k_histprep<<<NFRAG, 1024, 0, stream>>>(ei, priv, frag, W1, E);  // frag only
    k_zero<<<(N + 255) / 256, 256, 0, stream>>>(deg, N);
    k_hist_fb<<<2048, 256, 0, stream>>>(ei, deg, E);
    k_cvt<<<(N + 255) / 256, 256, 0, stream>>>(deg, wdeg, N);
  }
  k_main<<<MAIN_BLOCKS, 256, 0, stream>>>(X, frag, b1, wdeg, parts, N);
  k_red<<<RED_BLOCKS, 256, 0, stream>>>(parts, red, MAIN_BLOCKS / RED_BLOCKS);
  k_final<<<1, 1024, 0, stream>>>(red, RED_BLOCKS, W2, b2, Wp, bp,
                                  (float*)d_out, (float)N + (float)E,
                                  1.0f / (float)N);
}